// Round 9
// baseline (154.625 us; speedup 1.0000x reference)
//
#include <hip/hip_runtime.h>
#include <math.h>

// GCN layer: agg = D^-1/2 (A w) D^-1/2 x + x ; out = LayerNorm(gelu(agg @ W + b))
// N=10000, E=640000, D=128. fp32 in/out; edge_index int32.
//
// R9 = R8 with the feature-packing bug fixed: xs lane l now packs feats
// (l, l+64) — matching k_mega's acc[dl][l] / acc[dl][64+l] unpack — instead
// of R7's (2l, 2l+1) convention that scrambled features (R8 absmax 1.1).
//
// Measured laws driving this design:
//  R4: cooperative grid.sync ~50us/sync — banned.
//  R5: LDS fp32 atomicAdd = CAS loop — banned. LDS INT atomics are native.
//  R6: device-scope fp atomics write through to coherence point (320MB);
//      640k RANDOM global atomics ~110us; CONTIGUOUS reservation adds cheap.
//  R7: per-dst LDS sort + register accum = 52us k_mega (atomic-return
//      placement loop + 163k bank conflicts).
//  R8: xs packing convention MUST match the accumulator unpack convention.

#define D 128
#define NB 256       // buckets; nodes/bucket = 39..40
#define CAP 3136     // per-bucket edge capacity (mean 2500, +12 sigma)
#define FPSCALE 2097152.0f          // 2^21
#define FPINV   (1.0f / 2097152.0f)

static __device__ __forceinline__ unsigned int bf16bits(float v) {
    unsigned int u = __float_as_uint(v);
    return (u + 0x7fffu + ((u >> 16) & 1u)) >> 16;
}
static __device__ __forceinline__ int bkt_of(int d, unsigned N) {
    return (int)(((unsigned)d * NB) / N);
}
static __device__ __forceinline__ int bkt_start(int b, unsigned N) {
    return (int)(((unsigned)b * N + NB - 1) / NB);
}

// ---- K1: scatter edges into padded bucket regions (no random global atomics) ----
__global__ __launch_bounds__(1024) void k_scatter(const int* __restrict__ srcIdx,
                                                  const int* __restrict__ dstIdx,
                                                  const float* __restrict__ ew,
                                                  int* __restrict__ bucketcur,
                                                  uint2* __restrict__ tmp,
                                                  int E, unsigned N) {
    __shared__ int hist[NB];
    __shared__ int base[NB];
    int t = threadIdx.x;
    int stride = gridDim.x * 1024;
    if (t < NB) hist[t] = 0;
    __syncthreads();
    for (int e = blockIdx.x * 1024 + t; e < E; e += stride)
        atomicAdd(&hist[bkt_of(dstIdx[e], N)], 1);          // LDS, no return
    __syncthreads();
    if (t < NB) {
        int c = hist[t];
        base[t] = c ? atomicAdd(&bucketcur[t], c) : 0;      // contiguous global
        hist[t] = 0;                                        // running cursor
    }
    __syncthreads();
    for (int e = blockIdx.x * 1024 + t; e < E; e += stride) {
        int d = dstIdx[e];
        int bkt = bkt_of(d, N);
        int dl = d - bkt_start(bkt, N);                     // 0..39
        int off = atomicAdd(&hist[bkt], 1);                 // LDS return
        int pos = base[bkt] + off;
        if (pos < CAP)
            tmp[bkt * CAP + pos] = make_uint2((unsigned)srcIdx[e] | ((unsigned)dl << 16),
                                              __float_as_uint(ew[e]));
    }
}

// ---- K2: per-bucket deg hist -> deginv (global) -> pack xs lane l = (feat l, feat l+64) ----
__global__ __launch_bounds__(512) void k_xsdeg(const float* __restrict__ x,
                                               const uint2* __restrict__ tmp,
                                               const int* __restrict__ bucketcur,
                                               unsigned int* __restrict__ xs,
                                               float* __restrict__ deginv_g,
                                               unsigned N) {
    __shared__ int h[64];
    __shared__ float dinv[64];
    int b = blockIdx.x;
    int t = threadIdx.x;
    int start = bkt_start(b, N);
    int end = bkt_start(b + 1, N);
    int nn = end - start;                    // 39 or 40
    int cnt = bucketcur[b]; if (cnt > CAP) cnt = CAP;
    if (t < 64) h[t] = 0;
    __syncthreads();
    const uint2* bt = tmp + b * CAP;
    for (int i = t; i < cnt; i += 512)
        atomicAdd(&h[(bt[i].x >> 16) & 63], 1);
    __syncthreads();
    if (t < 64) dinv[t] = rsqrtf((float)h[t] + 1.0f);
    __syncthreads();
    if (t < nn) deginv_g[start + t] = dinv[t];
    int tot = nn * 64;
    for (int i = t; i < tot; i += 512) {
        int nl = i >> 6, l = i & 63;
        int node = start + nl;
        float s = dinv[nl];
        float f0 = x[node * D + l] * s;        // feat l
        float f1 = x[node * D + 64 + l] * s;   // feat l+64
        xs[node * 64 + l] = bf16bits(f0) | (bf16bits(f1) << 16);
    }
}

// ---- K3: fixed-point LDS-atomic aggregation + matvec + GELU + LN ----
__global__ __launch_bounds__(1024) void k_mega(
    const float* __restrict__ x, const unsigned int* __restrict__ xs,
    const uint2* __restrict__ tmp, const int* __restrict__ bucketcur,
    const float* __restrict__ deginv_g, const float* __restrict__ W,
    const float* __restrict__ bias, const float* __restrict__ gamma,
    const float* __restrict__ beta, float* __restrict__ out, unsigned N) {
    __shared__ int acc[40][D];           // 20 KB fixed-point accumulator
    __shared__ float aggs[8][D];         // 4 KB
    __shared__ float s1s[8][2], s2s[8][2];

    int b = blockIdx.x;
    int t = threadIdx.x;
    int start = bkt_start(b, N);
    int end = bkt_start(b + 1, N);
    int nn = end - start;
    int cnt = bucketcur[b]; if (cnt > CAP) cnt = CAP;
    const uint2* bt = tmp + b * CAP;

    for (int i = t; i < nn * D; i += 1024) ((int*)acc)[i] = 0;
    __syncthreads();

    int wv = t >> 6;        // wave 0..15
    int l = t & 63;         // lane

    // edge phase: wave wv takes 64-record batches strided by 16 waves
    for (int s0 = wv * 64; s0 < cnt; s0 += 16 * 64) {
        int m = cnt - s0; if (m > 64) m = 64;
        unsigned rx = 0; float rw = 0.0f;
        if (l < m) {
            uint2 rec = bt[s0 + l];
            rx = rec.x;
            rw = __uint_as_float(rec.y);
        }
#define ESTEP(j)                                                         \
        {                                                                \
            unsigned xj = (unsigned)__shfl((int)rx, (j), 64);            \
            float wj = __shfl(rw, (j), 64);                              \
            unsigned xp = xs[(xj & 0xffffu) * 64u + (unsigned)l];        \
            int dl = (int)((xj >> 16) & 63u);                            \
            float f0 = __uint_as_float(xp << 16) * wj;                   \
            float f1 = __uint_as_float(xp & 0xffff0000u) * wj;           \
            atomicAdd(&acc[dl][l], (int)(f0 * FPSCALE));                 \
            atomicAdd(&acc[dl][64 + l], (int)(f1 * FPSCALE));            \
        }
        if (m == 64) {
#pragma unroll 8
            for (int j = 0; j < 64; ++j) ESTEP(j)
        } else {
            for (int j = 0; j < m; ++j) ESTEP(j)
        }
#undef ESTEP
    }
    __syncthreads();

    // epilogue: group g (128 thr) handles dl = r*8+g, r = 0..4
    int g = t >> 7;
    int tt = t & 127;
    int w2 = (t >> 6) & 1;
    for (int r = 0; r < 5; ++r) {
        int dl = r * 8 + g;
        int node = start + dl;
        bool valid = dl < nn;
        float aggv = 0.0f;
        if (valid)
            aggv = (float)acc[dl][tt] * FPINV * deginv_g[node] + x[node * D + tt];
        aggs[g][tt] = aggv;
        __syncthreads();
        float hh = bias[tt];
#pragma unroll 8
        for (int k = 0; k < D; ++k)
            hh = fmaf(aggs[g][k], W[k * D + tt], hh);
        hh = 0.5f * hh * (1.0f + erff(hh * 0.70710678118654752f));
        float v1 = hh, v2 = hh * hh;
#pragma unroll
        for (int o = 32; o > 0; o >>= 1) {
            v1 += __shfl_xor(v1, o, 64);
            v2 += __shfl_xor(v2, o, 64);
        }
        if (l == 0) { s1s[g][w2] = v1; s2s[g][w2] = v2; }
        __syncthreads();
        float s1 = s1s[g][0] + s1s[g][1];
        float s2 = s2s[g][0] + s2s[g][1];
        float mu = s1 * (1.0f / D);
        float var = s2 * (1.0f / D) - mu * mu;
        float rinv = rsqrtf(var + 1e-5f);
        if (valid) out[node * D + tt] = (hh - mu) * rinv * gamma[tt] + beta[tt];
        __syncthreads();
    }
}

static inline size_t align256(size_t v) { return (v + 255) & ~(size_t)255; }

extern "C" void kernel_launch(void* const* d_in, const int* in_sizes, int n_in,
                              void* d_out, int out_size, void* d_ws, size_t ws_size,
                              hipStream_t stream) {
    const float* x     = (const float*)d_in[0];
    const int*   ei    = (const int*)d_in[1];
    const float* ew    = (const float*)d_in[2];
    const float* W     = (const float*)d_in[3];
    const float* b     = (const float*)d_in[4];
    const float* gamma = (const float*)d_in[5];
    const float* beta  = (const float*)d_in[6];
    float* out = (float*)d_out;

    const int E = in_sizes[2];       // 640000
    const unsigned N = (unsigned)(in_sizes[0] / D);   // 10000
    const int* srcIdx = ei;
    const int* dstIdx = ei + E;

    char* ws = (char*)d_ws;
    size_t off = 0;
    int* bucketcur = (int*)(ws + off);             off += align256((size_t)NB * 4);
    uint2* tmp = (uint2*)(ws + off);               off += align256((size_t)NB * CAP * 8);
    unsigned int* xs = (unsigned int*)(ws + off);  off += align256((size_t)N * 64 * 4);
    float* deginv_g = (float*)(ws + off);          off += align256((size_t)N * 4);
    (void)ws_size; (void)n_in; (void)out_size;

    hipMemsetAsync(bucketcur, 0, NB * sizeof(int), stream);
    k_scatter<<<256, 1024, 0, stream>>>(srcIdx, dstIdx, ew, bucketcur, tmp, E, N);
    k_xsdeg<<<NB, 512, 0, stream>>>(x, tmp, bucketcur, xs, deginv_g, N);
    k_mega<<<NB, 1024, 0, stream>>>(x, xs, tmp, bucketcur, deginv_g, W, b, gamma, beta, out, N);
}

// Round 10
// 119.081 us; speedup vs baseline: 1.2985x; 1.2985x over previous
//
#include <hip/hip_runtime.h>
#include <math.h>

// GCN layer: agg = D^-1/2 (A w) D^-1/2 x + x ; out = LayerNorm(gelu(agg @ W + b))
// N=10000, E=640000, D=128. fp32 in/out; edge_index int32.
//
// R10 design:
//  k_scatter: per-block CONTIGUOUS 2500-edge chunk, block-local LDS counting
//    sort by bucket (NB=512), coalesced writes of records + per-block rowptr.
//    NO global atomics, NO memset, NO capacity clipping.
//  k_xsdeg:  per-bucket deg from the 256 segments -> pack xs (bf16 pairs
//    (feat l, feat l+64), R9-verified convention).
//  k_mega:   gather segments -> LDS, sort by dst, balanced per-wave contiguous
//    edge chunks with register run-accumulation + boundary flush (fixed-point
//    ds_add, ~3 flushes/wave), then h = agg @ W via MFMA 16x16x32 bf16
//    (W staged bf16-swizzled in LDS once), exact GELU, LayerNorm.
//
// Measured laws:
//  R4: cooperative grid.sync ~50us/sync — banned.
//  R5: LDS fp32 atomicAdd = CAS loop — banned; LDS INT atomics native.
//  R6: random global atomics ~110us/640k; fp atomics write through L2.
//  R9: per-EDGE ds_add on one LDS pipe = 73us; only flush at run boundaries.
//  R7: per-(group,round) W streaming from L2 = ~20us -> stage W in LDS + MFMA.
// MFMA layouts (verified, learn_hip m89/m120): A[m=lane&15][k=quad*8+j],
//  B[k=quad*8+j][n=lane&15], C/D col=lane&15 row=quad*4+reg.

#define D 128
#define NB 512          // dst buckets; nodes/bucket = 19..20
#define NBK 256         // scatter blocks
#define MAXCHUNK 2560   // >= ceil(E/NBK) = 2500
#define MAXB 1600       // per-bucket edge cap (mean 1250, +10 sigma)
#define FPSCALE 2097152.0f
#define FPINV (1.0f / 2097152.0f)

typedef short bf16x8 __attribute__((ext_vector_type(8)));
typedef float f32x4 __attribute__((ext_vector_type(4)));

static __device__ __forceinline__ unsigned bf16bits(float v) {
    unsigned u = __float_as_uint(v);
    return (u + 0x7fffu + ((u >> 16) & 1u)) >> 16;
}
static __device__ __forceinline__ int bkt_of(int d, unsigned N) {
    return (int)(((unsigned)d * NB) / N);
}
static __device__ __forceinline__ int bkt_start(int b, unsigned N) {
    return (int)(((unsigned)b * N + NB - 1) / NB);
}

// ---- K1: block-local counting sort of a contiguous edge chunk ----
__global__ __launch_bounds__(1024) void k_scatter(const int* __restrict__ srcIdx,
                                                  const int* __restrict__ dstIdx,
                                                  const float* __restrict__ ew,
                                                  uint2* __restrict__ tmp,
                                                  int* __restrict__ rp,
                                                  int E, int chunk, unsigned N) {
    __shared__ int hist[NB];
    __shared__ int scn[NB];
    __shared__ int cur[NB];
    __shared__ int dsts[MAXCHUNK];
    __shared__ uint2 sbuf[MAXCHUNK];
    int t = threadIdx.x, bb = blockIdx.x;
    int e0 = bb * chunk;
    int e1 = e0 + chunk; if (e1 > E) e1 = E;
    int n_loc = e1 - e0; if (n_loc < 0) n_loc = 0;
    for (int i = t; i < NB; i += 1024) hist[i] = 0;
    __syncthreads();
    for (int i = t; i < n_loc; i += 1024) {
        int d = dstIdx[e0 + i];
        dsts[i] = d;
        atomicAdd(&hist[bkt_of(d, N)], 1);          // LDS, no return
    }
    __syncthreads();
    if (t < NB) scn[t] = hist[t];
    __syncthreads();
    for (int o = 1; o < NB; o <<= 1) {              // inclusive scan
        int v = 0;
        if (t < NB && t >= o) v = scn[t - o];
        __syncthreads();
        if (t < NB && t >= o) scn[t] += v;
        __syncthreads();
    }
    if (t < NB) {
        int excl = scn[t] - hist[t];
        cur[t] = excl;
        rp[bb * (NB + 1) + t] = excl;
    }
    if (t == 0) rp[bb * (NB + 1) + NB] = n_loc;
    __syncthreads();
    for (int i = t; i < n_loc; i += 1024) {         // place into LDS (sorted)
        int d = dsts[i];
        int bin = bkt_of(d, N);
        int dl = d - bkt_start(bin, N);             // 0..19
        int pos = atomicAdd(&cur[bin], 1);          // LDS return
        sbuf[pos] = make_uint2((unsigned)srcIdx[e0 + i] | ((unsigned)dl << 16),
                               __float_as_uint(ew[e0 + i]));
    }
    __syncthreads();
    for (int i = t; i < n_loc; i += 1024)           // coalesced write-out
        tmp[e0 + i] = sbuf[i];
}

// ---- K2: per-bucket degree from segments -> deginv -> pack xs ----
// xs[n*64+l]: low16 = bf16(x[n][l]*dinv[n]), high16 = bf16(x[n][l+64]*dinv[n]).
__global__ __launch_bounds__(256) void k_xsdeg(const float* __restrict__ x,
                                               const uint2* __restrict__ tmp,
                                               const int* __restrict__ rp,
                                               unsigned* __restrict__ xs,
                                               int chunk, unsigned N) {
    __shared__ int segoff[NBK];    // inclusive scan of segment lengths
    __shared__ int segsrc[NBK];
    __shared__ int h[24];
    __shared__ float dinv[24];
    int b = blockIdx.x, t = threadIdx.x;
    int start = bkt_start(b, N), end = bkt_start(b + 1, N);
    int nn = end - start;
    if (t < NBK) {
        int lo = rp[t * (NB + 1) + b];
        int hi = rp[t * (NB + 1) + b + 1];
        segoff[t] = hi - lo;
        segsrc[t] = t * chunk + lo;
    }
    if (t < 24) h[t] = 0;
    __syncthreads();
    for (int o = 1; o < NBK; o <<= 1) {
        int v = 0;
        if (t < NBK && t >= o) v = segoff[t - o];
        __syncthreads();
        if (t < NBK && t >= o) segoff[t] += v;
        __syncthreads();
    }
    int cnt = segoff[NBK - 1];
    for (int i = t; i < cnt; i += 256) {
        int lo2 = 0, hi2 = NBK - 1;                 // smallest s: segoff[s] > i
        while (lo2 < hi2) { int mid = (lo2 + hi2) >> 1; if (segoff[mid] > i) hi2 = mid; else lo2 = mid + 1; }
        int base = lo2 ? segoff[lo2 - 1] : 0;
        uint2 rec = tmp[segsrc[lo2] + (i - base)];
        atomicAdd(&h[rec.x >> 16], 1);
    }
    __syncthreads();
    if (t < nn) dinv[t] = rsqrtf((float)h[t] + 1.0f);
    __syncthreads();
    for (int i = t; i < nn * 64; i += 256) {
        int nl = i >> 6, l = i & 63;
        int node = start + nl;
        float s = dinv[nl];
        float f0 = x[node * D + l] * s;
        float f1 = x[node * D + 64 + l] * s;
        xs[node * 64 + l] = bf16bits(f0) | (bf16bits(f1) << 16);
    }
}

// ---- K3: gather+sort -> balanced run-accumulate -> MFMA -> GELU -> LN ----
__global__ __launch_bounds__(512) void k_mega(
    const float* __restrict__ x, const unsigned* __restrict__ xs,
    const uint2* __restrict__ tmp, const int* __restrict__ rp,
    const float* __restrict__ W, const float* __restrict__ bias,
    const float* __restrict__ gamma, const float* __restrict__ beta,
    float* __restrict__ out, int chunk, unsigned N) {
    __shared__ unsigned short wb[16384];   // 32 KB: Wb_sw[g=k>>3][n][j=k&7] bf16
    __shared__ int segoff[NBK];
    __shared__ int segsrc[NBK];
    __shared__ uint2 reg1[MAXB];           // fin2 raw; later hls float[20*129]
    __shared__ unsigned reg2[2176];        // fin sorted u32; later absb ushort[32*136]
    __shared__ int acc[20 * 128];          // fixed-point feature accumulator
    __shared__ int h[24], st[24], cur[24];
    __shared__ float dinvs[24];
    __shared__ float bias_s[128], gamma_s[128], beta_s[128];
    __shared__ float s1s[4][2], s2s[4][2];

    float* hls = (float*)reg1;             // [20][129] padded
    unsigned short* absb = (unsigned short*)reg2;  // [32][136] padded bf16
    unsigned* fin = reg2;                  // sorted records: src | bf16(ew)<<16

    int b = blockIdx.x, t = threadIdx.x;
    int start = bkt_start(b, N), end = bkt_start(b + 1, N);
    int nn = end - start;
    int wv = t >> 6, l = t & 63;

    // P0: stage W as swizzled bf16 + bias/gamma/beta
    for (int idx = t; idx < D * D; idx += 512) {
        int k = idx >> 7, n = idx & 127;
        wb[((k >> 3) * 128 + n) * 8 + (k & 7)] = (unsigned short)bf16bits(W[idx]);
    }
    if (t < 128) { bias_s[t] = bias[t]; gamma_s[t] = gamma[t]; beta_s[t] = beta[t]; }
    if (t < 24) h[t] = 0;

    // P1: segment table + scan
    if (t < NBK) {
        int lo = rp[t * (NB + 1) + b];
        int hi = rp[t * (NB + 1) + b + 1];
        segoff[t] = hi - lo;
        segsrc[t] = t * chunk + lo;
    }
    __syncthreads();
    for (int o = 1; o < NBK; o <<= 1) {
        int v = 0;
        if (t < NBK && t >= o) v = segoff[t - o];
        __syncthreads();
        if (t < NBK && t >= o) segoff[t] += v;
        __syncthreads();
    }
    int cnt = segoff[NBK - 1];
    int cntc = cnt > MAXB ? MAXB : cnt;

    // P2: gather records into LDS + per-dst histogram
    for (int i = t; i < cntc; i += 512) {
        int lo2 = 0, hi2 = NBK - 1;
        while (lo2 < hi2) { int mid = (lo2 + hi2) >> 1; if (segoff[mid] > i) hi2 = mid; else lo2 = mid + 1; }
        int base = lo2 ? segoff[lo2 - 1] : 0;
        uint2 rec = tmp[segsrc[lo2] + (i - base)];
        reg1[i] = rec;
        atomicAdd(&h[rec.x >> 16], 1);
    }
    // zero acc
    for (int i = t; i < 20 * 128; i += 512) acc[i] = 0;
    __syncthreads();

    // P3: serial scan over <=20 dst counts (one thread; trivial)
    if (t == 0) {
        st[0] = 0;
        for (int d2 = 0; d2 < nn; ++d2) st[d2 + 1] = st[d2] + h[d2];
    }
    if (t < nn) dinvs[t] = rsqrtf((float)h[t] + 1.0f);
    __syncthreads();
    if (t < nn) cur[t] = st[t];
    __syncthreads();

    // P4: place sorted-by-dst records: fin[pos] = src | bf16(ew)<<16
    for (int i = t; i < cntc; i += 512) {
        uint2 rec = reg1[i];
        int dl = (int)(rec.x >> 16);
        int pos = atomicAdd(&cur[dl], 1);
        fin[pos] = (rec.x & 0xffffu) | (bf16bits(__uint_as_float(rec.y)) << 16);
    }
    __syncthreads();

    // P5: balanced edge loop. Wave wv takes [lo,hi) of the sorted stream,
    // register-accumulates runs, flushes at dst boundaries (fixed-point ds_add).
    {
        int lo = (int)(((long long)cntc * wv) >> 3);
        int hi = (int)(((long long)cntc * (wv + 1)) >> 3);
        if (lo < hi) {
            int dl = 0;
            while (st[dl + 1] <= lo) ++dl;
            float a0 = 0.0f, a1 = 0.0f;
            int i = lo;
            while (i < hi) {
                if (i >= st[dl + 1]) {
                    atomicAdd(&acc[dl * 128 + l], (int)(a0 * FPSCALE));
                    atomicAdd(&acc[dl * 128 + 64 + l], (int)(a1 * FPSCALE));
                    a0 = 0.0f; a1 = 0.0f;
                    do { ++dl; } while (i >= st[dl + 1]);
                }
                int stop = st[dl + 1] < hi ? st[dl + 1] : hi;
                for (; i + 4 <= stop; i += 4) {
                    unsigned p0 = fin[i], p1 = fin[i + 1], p2 = fin[i + 2], p3 = fin[i + 3];
                    unsigned q0 = xs[(p0 & 0xffffu) * 64u + (unsigned)l];
                    unsigned q1 = xs[(p1 & 0xffffu) * 64u + (unsigned)l];
                    unsigned q2 = xs[(p2 & 0xffffu) * 64u + (unsigned)l];
                    unsigned q3 = xs[(p3 & 0xffffu) * 64u + (unsigned)l];
                    float w0 = __uint_as_float(p0 & 0xffff0000u);
                    float w1 = __uint_as_float(p1 & 0xffff0000u);
                    float w2 = __uint_as_float(p2 & 0xffff0000u);
                    float w3 = __uint_as_float(p3 & 0xffff0000u);
                    a0 = fmaf(__uint_as_float(q0 << 16), w0, a0);
                    a1 = fmaf(__uint_as_float(q0 & 0xffff0000u), w0, a1);
                    a0 = fmaf(__uint_as_float(q1 << 16), w1, a0);
                    a1 = fmaf(__uint_as_float(q1 & 0xffff0000u), w1, a1);
                    a0 = fmaf(__uint_as_float(q2 << 16), w2, a0);
                    a1 = fmaf(__uint_as_float(q2 & 0xffff0000u), w2, a1);
                    a0 = fmaf(__uint_as_float(q3 << 16), w3, a0);
                    a1 = fmaf(__uint_as_float(q3 & 0xffff0000u), w3, a1);
                }
                for (; i < stop; ++i) {
                    unsigned p = fin[i];
                    float wt = __uint_as_float(p & 0xffff0000u);
                    unsigned q = xs[(p & 0xffffu) * 64u + (unsigned)l];
                    a0 = fmaf(__uint_as_float(q << 16), wt, a0);
                    a1 = fmaf(__uint_as_float(q & 0xffff0000u), wt, a1);
                }
            }
            atomicAdd(&acc[dl * 128 + l], (int)(a0 * FPSCALE));
            atomicAdd(&acc[dl * 128 + 64 + l], (int)(a1 * FPSCALE));
        }
    }
    __syncthreads();

    // P6: agg = acc*FPINV*dinv + x  -> absb bf16 [32][136] (pad rows zero)
    for (int i = t; i < 32 * 128; i += 512) {
        int row = i >> 7, col = i & 127;
        unsigned short v = 0;
        if (row < nn) {
            float aggv = (float)acc[row * 128 + col] * FPINV * dinvs[row]
                         + x[(start + row) * D + col];
            v = (unsigned short)bf16bits(aggv);
        }
        absb[row * 136 + col] = v;
    }
    __syncthreads();

    // P7: h = agg @ W via MFMA 16x16x32 bf16; + bias, exact GELU -> hls
    {
        int col = l & 15, quad = l >> 4;
#pragma unroll
        for (int ti = 0; ti < 2; ++ti) {
            int tid = wv * 2 + ti;          // 0..15
            int mt = tid >> 3, nt = tid & 7;
            f32x4 dacc = {0.0f, 0.0f, 0.0f, 0.0f};
#pragma unroll
            for (int kk = 0; kk < 4; ++kk) {
                bf16x8 av = *(const bf16x8*)&absb[(mt * 16 + col) * 136 + kk * 32 + quad * 8];
                bf16x8 bv = *(const bf16x8*)&wb[((kk * 4 + quad) * 128 + nt * 16 + col) * 8];
                dacc = __builtin_amdgcn_mfma_f32_16x16x32_bf16(av, bv, dacc, 0, 0, 0);
            }
#pragma unroll
            for (int r = 0; r < 4; ++r) {
                int m = mt * 16 + quad * 4 + r;
                int n = nt * 16 + col;
                if (m < 20) {
                    float hh = dacc[r] + bias_s[n];
                    hh = 0.5f * hh * (1.0f + erff(hh * 0.70710678f));
                    hls[m * 129 + n] = hh;
                }
            }
        }
    }
    __syncthreads();

    // P8: LayerNorm per dst row; groups of 128 threads, 5 rounds
    {
        int g = t >> 7;          // 0..3
        int tt = t & 127;
        int w2 = (t >> 6) & 1;
        for (int r = 0; r < 5; ++r) {
            int dl = r * 4 + g;
            bool valid = dl < nn;
            float hh = valid ? hls[dl * 129 + tt] : 0.0f;
            float v1 = hh, v2 = hh * hh;
#pragma unroll
            for (int o = 32; o > 0; o >>= 1) {
                v1 += __shfl_xor(v1, o, 64);
                v2 += __shfl_xor(v2, o, 64);
            }
            if (l == 0) { s1s[g][w2] = v1; s2s[g][w2] = v2; }
            __syncthreads();
            float s1 = s1s[g][0] + s1s[g][1];
            float s2 = s2s[g][0] + s2s[g][1];
            float mu = s1 * (1.0f / D);
            float var = s2 * (1.0f / D) - mu * mu;
            float rinv = rsqrtf(var + 1e-5f);
            if (valid)
                out[(start + dl) * D + tt] = (hh - mu) * rinv * gamma_s[tt] + beta_s[tt];
            __syncthreads();
        }
    }
}

static inline size_t align256(size_t v) { return (v + 255) & ~(size_t)255; }

extern "C" void kernel_launch(void* const* d_in, const int* in_sizes, int n_in,
                              void* d_out, int out_size, void* d_ws, size_t ws_size,
                              hipStream_t stream) {
    const float* x     = (const float*)d_in[0];
    const int*   ei    = (const int*)d_in[1];
    const float* ew    = (const float*)d_in[2];
    const float* W     = (const float*)d_in[3];
    const float* b     = (const float*)d_in[4];
    const float* gamma = (const float*)d_in[5];
    const float* beta  = (const float*)d_in[6];
    float* out = (float*)d_out;

    const int E = in_sizes[2];                        // 640000
    const unsigned N = (unsigned)(in_sizes[0] / D);   // 10000
    const int chunk = (E + NBK - 1) / NBK;            // 2500
    const int* srcIdx = ei;
    const int* dstIdx = ei + E;

    char* ws = (char*)d_ws;
    size_t off = 0;
    uint2* tmp = (uint2*)(ws + off);        off += align256((size_t)E * 8);
    int* rp = (int*)(ws + off);             off += align256((size_t)NBK * (NB + 1) * 4);
    unsigned* xs = (unsigned*)(ws + off);   off += align256((size_t)N * 64 * 4);
    (void)ws_size; (void)n_in; (void)out_size;

    k_scatter<<<NBK, 1024, 0, stream>>>(srcIdx, dstIdx, ew, tmp, rp, E, chunk, N);
    k_xsdeg<<<NB, 256, 0, stream>>>(x, tmp, rp, xs, chunk, N);
    k_mega<<<NB, 512, 0, stream>>>(x, xs, tmp, rp, W, b, gamma, beta, out, chunk, N);
}

// Round 11
// 114.836 us; speedup vs baseline: 1.3465x; 1.0370x over previous
//
#include <hip/hip_runtime.h>
#include <math.h>

// GCN layer: agg = D^-1/2 (A w) D^-1/2 x + x ; out = LayerNorm(gelu(agg @ W + b))
// N=10000, E=640000, D=128. fp32 in/out; edge_index int32.
//
// R11: single gather + single sort.
//  k_scatter: (unchanged R10) per-block contiguous chunk, block-local LDS
//    counting sort by bucket (NB=512), coalesced tmp + per-block rowptr.
//  k_build:   per-bucket: segment scan + binsearch gather (ONCE), dst hist,
//    LDS counting sort -> writes contiguous dst-SORTED fin stream (4-B
//    src|bf16(ew)) + st[21] boundary table + packed xs. deginv = from st.
//  k_mega:    coalesced fin->LDS, balanced per-wave contiguous chunks over
//    sorted stream, register run-accum + fixed-point ds_add flush at dst
//    boundaries (unroll 8), then h = agg@W via MFMA 16x16x32 bf16 (W staged
//    in LDS), exact GELU, LayerNorm.
//
// Measured laws:
//  R4: cooperative grid.sync ~50us/sync — banned.
//  R5: LDS fp32 atomicAdd = CAS loop — banned; LDS INT atomics native.
//  R6: random global atomics ~110us/640k; fp atomics write through L2.
//  R9: per-EDGE ds_add = 73us; flush only at run boundaries.
//  R7: W streaming per group-round from L2 ~20us -> stage W in LDS + MFMA.

#define D 128
#define NB 512          // dst buckets; nodes/bucket = 19..20
#define NBK 256         // scatter blocks
#define MAXCHUNK 2560   // >= ceil(E/NBK) = 2500
#define MAXB 1600       // per-bucket edge cap (mean 1250, +10 sigma)
#define FPSCALE 2097152.0f
#define FPINV (1.0f / 2097152.0f)

typedef short bf16x8 __attribute__((ext_vector_type(8)));
typedef float f32x4 __attribute__((ext_vector_type(4)));

static __device__ __forceinline__ unsigned bf16bits(float v) {
    unsigned u = __float_as_uint(v);
    return (u + 0x7fffu + ((u >> 16) & 1u)) >> 16;
}
static __device__ __forceinline__ int bkt_of(int d, unsigned N) {
    return (int)(((unsigned)d * NB) / N);
}
static __device__ __forceinline__ int bkt_start(int b, unsigned N) {
    return (int)(((unsigned)b * N + NB - 1) / NB);
}

// ---- K1: block-local counting sort of a contiguous edge chunk (R10) ----
__global__ __launch_bounds__(1024) void k_scatter(const int* __restrict__ srcIdx,
                                                  const int* __restrict__ dstIdx,
                                                  const float* __restrict__ ew,
                                                  uint2* __restrict__ tmp,
                                                  int* __restrict__ rp,
                                                  int E, int chunk, unsigned N) {
    __shared__ int hist[NB];
    __shared__ int scn[NB];
    __shared__ int cur[NB];
    __shared__ int dsts[MAXCHUNK];
    __shared__ uint2 sbuf[MAXCHUNK];
    int t = threadIdx.x, bb = blockIdx.x;
    int e0 = bb * chunk;
    int e1 = e0 + chunk; if (e1 > E) e1 = E;
    int n_loc = e1 - e0; if (n_loc < 0) n_loc = 0;
    for (int i = t; i < NB; i += 1024) hist[i] = 0;
    __syncthreads();
    for (int i = t; i < n_loc; i += 1024) {
        int d = dstIdx[e0 + i];
        dsts[i] = d;
        atomicAdd(&hist[bkt_of(d, N)], 1);
    }
    __syncthreads();
    if (t < NB) scn[t] = hist[t];
    __syncthreads();
    for (int o = 1; o < NB; o <<= 1) {
        int v = 0;
        if (t < NB && t >= o) v = scn[t - o];
        __syncthreads();
        if (t < NB && t >= o) scn[t] += v;
        __syncthreads();
    }
    if (t < NB) {
        int excl = scn[t] - hist[t];
        cur[t] = excl;
        rp[bb * (NB + 1) + t] = excl;
    }
    if (t == 0) rp[bb * (NB + 1) + NB] = n_loc;
    __syncthreads();
    for (int i = t; i < n_loc; i += 1024) {
        int d = dsts[i];
        int bin = bkt_of(d, N);
        int dl = d - bkt_start(bin, N);
        int pos = atomicAdd(&cur[bin], 1);
        sbuf[pos] = make_uint2((unsigned)srcIdx[e0 + i] | ((unsigned)dl << 16),
                               __float_as_uint(ew[e0 + i]));
    }
    __syncthreads();
    for (int i = t; i < n_loc; i += 1024)
        tmp[e0 + i] = sbuf[i];
}

// ---- K2: per-bucket gather (once) -> hist -> sort -> fin/st/xs ----
__global__ __launch_bounds__(256) void k_build(const float* __restrict__ x,
                                               const uint2* __restrict__ tmp,
                                               const int* __restrict__ rp,
                                               unsigned* __restrict__ fin_g,
                                               int* __restrict__ stg,
                                               unsigned* __restrict__ xs,
                                               int chunk, unsigned N) {
    __shared__ int segoff[NBK];
    __shared__ int segsrc[NBK];
    __shared__ uint2 buf[MAXB];       // 12.8 KB raw records
    __shared__ unsigned finL[MAXB];   // 6.4 KB sorted output
    __shared__ int h[24], st[24], cur[24];
    __shared__ float dinv[24];
    int b = blockIdx.x, t = threadIdx.x;
    int start = bkt_start(b, N), end = bkt_start(b + 1, N);
    int nn = end - start;
    if (t < NBK) {
        int lo = rp[t * (NB + 1) + b];
        int hi = rp[t * (NB + 1) + b + 1];
        segoff[t] = hi - lo;
        segsrc[t] = t * chunk + lo;
    }
    if (t < 24) h[t] = 0;
    __syncthreads();
    for (int o = 1; o < NBK; o <<= 1) {
        int v = 0;
        if (t < NBK && t >= o) v = segoff[t - o];
        __syncthreads();
        if (t < NBK && t >= o) segoff[t] += v;
        __syncthreads();
    }
    int cnt = segoff[NBK - 1];
    int cntc = cnt > MAXB ? MAXB : cnt;
    for (int i = t; i < cntc; i += 256) {
        int lo2 = 0, hi2 = NBK - 1;
        while (lo2 < hi2) { int mid = (lo2 + hi2) >> 1; if (segoff[mid] > i) hi2 = mid; else lo2 = mid + 1; }
        int base = lo2 ? segoff[lo2 - 1] : 0;
        uint2 rec = tmp[segsrc[lo2] + (i - base)];
        buf[i] = rec;
        atomicAdd(&h[rec.x >> 16], 1);
    }
    __syncthreads();
    if (t == 0) {
        st[0] = 0;
        for (int d2 = 0; d2 < nn; ++d2) st[d2 + 1] = st[d2] + h[d2];
    }
    if (t < nn) dinv[t] = rsqrtf((float)h[t] + 1.0f);
    __syncthreads();
    if (t < nn) cur[t] = st[t];
    __syncthreads();
    for (int i = t; i < cntc; i += 256) {
        uint2 rec = buf[i];
        int dl = (int)(rec.x >> 16);
        int pos = atomicAdd(&cur[dl], 1);
        finL[pos] = (rec.x & 0xffffu) | (bf16bits(__uint_as_float(rec.y)) << 16);
    }
    __syncthreads();
    for (int i = t; i < cntc; i += 256)
        fin_g[b * MAXB + i] = finL[i];
    if (t <= nn) stg[b * 32 + t] = st[t];
    // xs pack: lane l packs (feat l, feat l+64) scaled by deginv
    for (int i = t; i < nn * 64; i += 256) {
        int nl = i >> 6, l = i & 63;
        int node = start + nl;
        float s = dinv[nl];
        float f0 = x[node * D + l] * s;
        float f1 = x[node * D + 64 + l] * s;
        xs[node * 64 + l] = bf16bits(f0) | (bf16bits(f1) << 16);
    }
}

// ---- K3: sorted-stream aggregation + MFMA + GELU + LN ----
__global__ __launch_bounds__(512) void k_mega(
    const float* __restrict__ x, const unsigned* __restrict__ xs,
    const unsigned* __restrict__ fin_g, const int* __restrict__ stg,
    const float* __restrict__ W, const float* __restrict__ bias,
    const float* __restrict__ gamma, const float* __restrict__ beta,
    float* __restrict__ out, unsigned N) {
    __shared__ unsigned short wb[16384];        // 32 KB swizzled bf16 W
    __shared__ __align__(16) char regA[8704];   // finL u32 | absb u16[32][136]
    __shared__ __align__(16) char regB[10320];  // acc int[20][128] | hls f32[20][129]
    __shared__ int st[24];
    __shared__ float bias_s[128], gamma_s[128], beta_s[128];
    __shared__ float s1s[4][2], s2s[4][2];

    unsigned* finL = (unsigned*)regA;
    unsigned short* absb = (unsigned short*)regA;
    int* acc = (int*)regB;
    float* hls = (float*)regB;

    int b = blockIdx.x, t = threadIdx.x;
    int start = bkt_start(b, N), end = bkt_start(b + 1, N);
    int nn = end - start;
    int wv = t >> 6, l = t & 63;

    // P0: stage W swizzled bf16; bias/gamma/beta; st table
    for (int idx = t; idx < D * D; idx += 512) {
        int k = idx >> 7, n = idx & 127;
        wb[((k >> 3) * 128 + n) * 8 + (k & 7)] = (unsigned short)bf16bits(W[idx]);
    }
    if (t < 128) { bias_s[t] = bias[t]; gamma_s[t] = gamma[t]; beta_s[t] = beta[t]; }
    if (t <= nn) st[t] = stg[b * 32 + t];
    for (int i = t; i < 20 * 128; i += 512) acc[i] = 0;
    __syncthreads();
    int cntc = st[nn];
    // P1: coalesced fin load
    for (int i = t; i < cntc; i += 512) finL[i] = fin_g[b * MAXB + i];
    __syncthreads();

    // P2: balanced edge loop over sorted stream; register runs, flush at
    // dst boundaries with fixed-point ds_add.
    {
        int lo = (int)(((long long)cntc * wv) >> 3);
        int hi = (int)(((long long)cntc * (wv + 1)) >> 3);
        if (lo < hi) {
            int dl = 0;
            while (st[dl + 1] <= lo) ++dl;
            float a0 = 0.0f, a1 = 0.0f;
            int i = lo;
            while (i < hi) {
                if (i >= st[dl + 1]) {
                    atomicAdd(&acc[dl * 128 + l], (int)(a0 * FPSCALE));
                    atomicAdd(&acc[dl * 128 + 64 + l], (int)(a1 * FPSCALE));
                    a0 = 0.0f; a1 = 0.0f;
                    do { ++dl; } while (i >= st[dl + 1]);
                }
                int stop = st[dl + 1] < hi ? st[dl + 1] : hi;
                for (; i + 8 <= stop; i += 8) {
                    unsigned p[8], q[8];
#pragma unroll
                    for (int j = 0; j < 8; ++j) p[j] = finL[i + j];
#pragma unroll
                    for (int j = 0; j < 8; ++j) q[j] = xs[(p[j] & 0xffffu) * 64u + (unsigned)l];
#pragma unroll
                    for (int j = 0; j < 8; ++j) {
                        float wt = __uint_as_float(p[j] & 0xffff0000u);
                        a0 = fmaf(__uint_as_float(q[j] << 16), wt, a0);
                        a1 = fmaf(__uint_as_float(q[j] & 0xffff0000u), wt, a1);
                    }
                }
                for (; i < stop; ++i) {
                    unsigned p = finL[i];
                    float wt = __uint_as_float(p & 0xffff0000u);
                    unsigned q = xs[(p & 0xffffu) * 64u + (unsigned)l];
                    a0 = fmaf(__uint_as_float(q << 16), wt, a0);
                    a1 = fmaf(__uint_as_float(q & 0xffff0000u), wt, a1);
                }
            }
            atomicAdd(&acc[dl * 128 + l], (int)(a0 * FPSCALE));
            atomicAdd(&acc[dl * 128 + 64 + l], (int)(a1 * FPSCALE));
        }
    }
    __syncthreads();

    // P3: agg = acc*FPINV*dinv + x -> absb bf16 [32][136] (pad rows zero)
    for (int i = t; i < 32 * 128; i += 512) {
        int row = i >> 7, col = i & 127;
        unsigned short v = 0;
        if (row < nn) {
            float dv = rsqrtf((float)(st[row + 1] - st[row]) + 1.0f);
            float aggv = (float)acc[row * 128 + col] * FPINV * dv
                         + x[(start + row) * D + col];
            v = (unsigned short)bf16bits(aggv);
        }
        absb[row * 136 + col] = v;
    }
    __syncthreads();

    // P4: h = agg @ W via MFMA 16x16x32 bf16; + bias, exact GELU -> hls
    {
        int col = l & 15, quad = l >> 4;
#pragma unroll
        for (int ti = 0; ti < 2; ++ti) {
            int tid = wv * 2 + ti;          // 0..15
            int mt = tid >> 3, nt = tid & 7;
            f32x4 dacc = {0.0f, 0.0f, 0.0f, 0.0f};
#pragma unroll
            for (int kk = 0; kk < 4; ++kk) {
                bf16x8 av = *(const bf16x8*)&absb[(mt * 16 + col) * 136 + kk * 32 + quad * 8];
                bf16x8 bv = *(const bf16x8*)&wb[((kk * 4 + quad) * 128 + nt * 16 + col) * 8];
                dacc = __builtin_amdgcn_mfma_f32_16x16x32_bf16(av, bv, dacc, 0, 0, 0);
            }
#pragma unroll
            for (int r = 0; r < 4; ++r) {
                int m = mt * 16 + quad * 4 + r;
                int n = nt * 16 + col;
                if (m < 20) {
                    float hh = dacc[r] + bias_s[n];
                    hh = 0.5f * hh * (1.0f + erff(hh * 0.70710678f));
                    hls[m * 129 + n] = hh;
                }
            }
        }
    }
    __syncthreads();

    // P5: LayerNorm per dst row; groups of 128 threads, 5 rounds
    {
        int g = t >> 7;
        int tt = t & 127;
        int w2 = (t >> 6) & 1;
        for (int r = 0; r < 5; ++r) {
            int dl = r * 4 + g;
            bool valid = dl < nn;
            float hh = valid ? hls[dl * 129 + tt] : 0.0f;
            float v1 = hh, v2 = hh * hh;
#pragma unroll
            for (int o = 32; o > 0; o >>= 1) {
                v1 += __shfl_xor(v1, o, 64);
                v2 += __shfl_xor(v2, o, 64);
            }
            if (l == 0) { s1s[g][w2] = v1; s2s[g][w2] = v2; }
            __syncthreads();
            float s1 = s1s[g][0] + s1s[g][1];
            float s2 = s2s[g][0] + s2s[g][1];
            float mu = s1 * (1.0f / D);
            float var = s2 * (1.0f / D) - mu * mu;
            float rinv = rsqrtf(var + 1e-5f);
            if (valid)
                out[(start + dl) * D + tt] = (hh - mu) * rinv * gamma_s[tt] + beta_s[tt];
            __syncthreads();
        }
    }
}

static inline size_t align256(size_t v) { return (v + 255) & ~(size_t)255; }

extern "C" void kernel_launch(void* const* d_in, const int* in_sizes, int n_in,
                              void* d_out, int out_size, void* d_ws, size_t ws_size,
                              hipStream_t stream) {
    const float* x     = (const float*)d_in[0];
    const int*   ei    = (const int*)d_in[1];
    const float* ew    = (const float*)d_in[2];
    const float* W     = (const float*)d_in[3];
    const float* b     = (const float*)d_in[4];
    const float* gamma = (const float*)d_in[5];
    const float* beta  = (const float*)d_in[6];
    float* out = (float*)d_out;

    const int E = in_sizes[2];                        // 640000
    const unsigned N = (unsigned)(in_sizes[0] / D);   // 10000
    const int chunk = (E + NBK - 1) / NBK;            // 2500
    const int* srcIdx = ei;
    const int* dstIdx = ei + E;

    char* ws = (char*)d_ws;
    size_t off = 0;
    uint2* tmp = (uint2*)(ws + off);        off += align256((size_t)E * 8);
    int* rp = (int*)(ws + off);             off += align256((size_t)NBK * (NB + 1) * 4);
    unsigned* xs = (unsigned*)(ws + off);   off += align256((size_t)N * 64 * 4);
    unsigned* fin_g = (unsigned*)(ws + off); off += align256((size_t)NB * MAXB * 4);
    int* stg = (int*)(ws + off);            off += align256((size_t)NB * 32 * 4);
    (void)ws_size; (void)n_in; (void)out_size;

    k_scatter<<<NBK, 1024, 0, stream>>>(srcIdx, dstIdx, ew, tmp, rp, E, chunk, N);
    k_build<<<NB, 256, 0, stream>>>(x, tmp, rp, fin_g, stg, xs, chunk, N);
    k_mega<<<NB, 512, 0, stream>>>(x, xs, fin_g, stg, W, b, gamma, beta, out, N);
}

// Round 12
// 112.017 us; speedup vs baseline: 1.3804x; 1.0252x over previous
//
#include <hip/hip_runtime.h>
#include <math.h>

// GCN layer: agg = D^-1/2 (A w) D^-1/2 x + x ; out = LayerNorm(gelu(agg @ W + b))
// N=10000, E=640000, D=128. fp32 in/out; edge_index int32.
//
// R12: instruction/barrier diet on the R11 structure.
//  k_scatter: wave-shfl scan (2 barriers, was ~18), no dsts[] staging; +8
//    tail blocks pre-swizzle W -> wb_g (bf16, MFMA-ready) once.
//  k_build:   512 thr; per-segment DIRECT copy (was per-record 8-step LDS
//    binsearch); wave-shfl segment scan; emits dst-sorted fin + st + xs.
//  k_mega:    wb_g -> LDS via coalesced uint4 copy (no per-block convert);
//    balanced sorted-stream edge loop (reg runs + fixed-point ds_add flush);
//    MFMA 16x16x32 bf16; LayerNorm one-wave-per-row (0 barriers, was 10).
//
// Measured laws:
//  R4: cooperative grid.sync ~50us/sync — banned.
//  R5: LDS fp32 atomicAdd = CAS loop — banned; LDS INT atomics native.
//  R6: random global atomics ~110us/640k; fp atomics write through L2.
//  R9: per-EDGE ds_add = 73us; flush only at run boundaries.
//  R7: per-block W streaming ~20us -> stage W in LDS + MFMA.

#define D 128
#define NB 512          // dst buckets; nodes/bucket = 19..20
#define NBK 256         // scatter blocks
#define MAXB 1600       // per-bucket edge cap (mean 1250, +10 sigma)
#define FPSCALE 2097152.0f
#define FPINV (1.0f / 2097152.0f)

typedef short bf16x8 __attribute__((ext_vector_type(8)));
typedef float f32x4 __attribute__((ext_vector_type(4)));

static __device__ __forceinline__ unsigned bf16bits(float v) {
    unsigned u = __float_as_uint(v);
    return (u + 0x7fffu + ((u >> 16) & 1u)) >> 16;
}
static __device__ __forceinline__ int bkt_of(int d, unsigned N) {
    return (int)(((unsigned)d * NB) / N);
}
static __device__ __forceinline__ int bkt_start(int b, unsigned N) {
    return (int)(((unsigned)b * N + NB - 1) / NB);
}

// ---- K1: block-local counting sort of a contiguous edge chunk + W swizzle ----
__global__ __launch_bounds__(1024) void k_scatter(const int* __restrict__ srcIdx,
                                                  const int* __restrict__ dstIdx,
                                                  const float* __restrict__ ew,
                                                  const float* __restrict__ W,
                                                  uint2* __restrict__ tmp,
                                                  int* __restrict__ rp,
                                                  unsigned short* __restrict__ wb_g,
                                                  int E, int chunk, unsigned N) {
    int t = threadIdx.x, bb = blockIdx.x;
    if (bb >= NBK) {   // tail blocks: W -> bf16 swizzled wb_g (once)
        int base = (bb - NBK) * 2048;
        for (int i = t; i < 2048; i += 1024) {
            int idx = base + i;
            int k = idx >> 7, n = idx & 127;
            wb_g[((k >> 3) * 128 + n) * 8 + (k & 7)] = (unsigned short)bf16bits(W[idx]);
        }
        return;
    }
    __shared__ int hist[NB];
    __shared__ int cur[NB];
    __shared__ uint2 sbuf[MAXB + 1024];   // chunk <= 2500
    __shared__ int wsum[8], wpre[8];
    int e0 = bb * chunk;
    int e1 = e0 + chunk; if (e1 > E) e1 = E;
    int n_loc = e1 - e0; if (n_loc < 0) n_loc = 0;
    int l = t & 63;
    if (t < NB) hist[t] = 0;
    __syncthreads();
    for (int i = t; i < n_loc; i += 1024)
        atomicAdd(&hist[bkt_of(dstIdx[e0 + i], N)], 1);     // LDS, no return
    __syncthreads();
    // wave-shfl inclusive scan of hist[512] (waves 0..7 own elements t<512)
    int v = 0, incl = 0;
    if (t < NB) {
        v = hist[t];
        incl = v;
        for (int o = 1; o < 64; o <<= 1) {
            int nb2 = __shfl_up(incl, o, 64);
            if (l >= o) incl += nb2;
        }
        if (l == 63) wsum[t >> 6] = incl;
    }
    __syncthreads();
    if (t < 8) {
        int p = 0;
        for (int i = 0; i < t; ++i) p += wsum[i];
        wpre[t] = p;
    }
    __syncthreads();
    if (t < NB) {
        int excl = incl - v + wpre[t >> 6];
        cur[t] = excl;
        rp[bb * (NB + 1) + t] = excl;
    }
    if (t == 0) rp[bb * (NB + 1) + NB] = n_loc;
    __syncthreads();
    for (int i = t; i < n_loc; i += 1024) {
        int d = dstIdx[e0 + i];
        int bin = bkt_of(d, N);
        int dl = d - bkt_start(bin, N);
        int pos = atomicAdd(&cur[bin], 1);                  // LDS return
        sbuf[pos] = make_uint2((unsigned)srcIdx[e0 + i] | ((unsigned)dl << 16),
                               __float_as_uint(ew[e0 + i]));
    }
    __syncthreads();
    for (int i = t; i < n_loc; i += 1024)
        tmp[e0 + i] = sbuf[i];
}

// ---- K2: per-bucket direct-segment gather -> hist -> sort -> fin/st/xs ----
__global__ __launch_bounds__(512) void k_build(const float* __restrict__ x,
                                               const uint2* __restrict__ tmp,
                                               const int* __restrict__ rp,
                                               unsigned* __restrict__ fin_g,
                                               int* __restrict__ stg,
                                               unsigned* __restrict__ xs,
                                               int chunk, unsigned N) {
    __shared__ uint2 buf[MAXB];       // 12.8 KB raw records
    __shared__ unsigned finL[MAXB];   // 6.4 KB sorted output
    __shared__ int h[24], st[24], cur[24];
    __shared__ float dinv[24];
    __shared__ int wsum[4], wpre[4];
    int b = blockIdx.x, t = threadIdx.x;
    int start = bkt_start(b, N), end = bkt_start(b + 1, N);
    int nn = end - start;
    int l = t & 63;
    int seglen = 0, segsrc = 0;
    if (t < NBK) {
        int lo = rp[t * (NB + 1) + b];
        int hi = rp[t * (NB + 1) + b + 1];
        seglen = hi - lo;
        segsrc = t * chunk + lo;
    }
    if (t < 24) h[t] = 0;
    // wave-shfl scan of 256 segment lengths (waves 0..3)
    int incl = seglen;
    if (t < NBK) {
        for (int o = 1; o < 64; o <<= 1) {
            int nb2 = __shfl_up(incl, o, 64);
            if (l >= o) incl += nb2;
        }
        if (l == 63) wsum[t >> 6] = incl;
    }
    __syncthreads();
    if (t < 4) {
        int p = 0;
        for (int i = 0; i < t; ++i) p += wsum[i];
        wpre[t] = p;
    }
    __syncthreads();
    int cnt = wsum[0] + wsum[1] + wsum[2] + wsum[3];
    int cntc = cnt > MAXB ? MAXB : cnt;
    // direct per-segment copy + per-dst histogram
    if (t < NBK && seglen > 0) {
        int base = incl - seglen + wpre[t >> 6];
        for (int k2 = 0; k2 < seglen; ++k2) {
            int pos = base + k2;
            if (pos < MAXB) {
                uint2 rec = tmp[segsrc + k2];
                buf[pos] = rec;
                atomicAdd(&h[rec.x >> 16], 1);
            }
        }
    }
    __syncthreads();
    if (t == 0) {
        st[0] = 0;
        for (int d2 = 0; d2 < nn; ++d2) st[d2 + 1] = st[d2] + h[d2];
    }
    if (t < nn) dinv[t] = rsqrtf((float)h[t] + 1.0f);
    __syncthreads();
    if (t < nn) cur[t] = st[t];
    __syncthreads();
    for (int i = t; i < cntc; i += 512) {
        uint2 rec = buf[i];
        int dl = (int)(rec.x >> 16);
        int pos = atomicAdd(&cur[dl], 1);
        finL[pos] = (rec.x & 0xffffu) | (bf16bits(__uint_as_float(rec.y)) << 16);
    }
    __syncthreads();
    for (int i = t; i < cntc; i += 512)
        fin_g[b * MAXB + i] = finL[i];
    if (t <= nn) stg[b * 32 + t] = st[t];
    // xs pack: lane l packs (feat l, feat l+64) scaled by deginv
    for (int i = t; i < nn * 64; i += 512) {
        int nl = i >> 6, ll = i & 63;
        int node = start + nl;
        float s = dinv[nl];
        float f0 = x[node * D + ll] * s;
        float f1 = x[node * D + 64 + ll] * s;
        xs[node * 64 + ll] = bf16bits(f0) | (bf16bits(f1) << 16);
    }
}

// ---- K3: sorted-stream aggregation + MFMA + GELU + LN ----
__global__ __launch_bounds__(512) void k_mega(
    const float* __restrict__ x, const unsigned* __restrict__ xs,
    const unsigned* __restrict__ fin_g, const int* __restrict__ stg,
    const unsigned short* __restrict__ wb_g, const float* __restrict__ bias,
    const float* __restrict__ gamma, const float* __restrict__ beta,
    float* __restrict__ out, unsigned N) {
    __shared__ __align__(16) unsigned short wb[16384];   // 32 KB swizzled bf16 W
    __shared__ __align__(16) char regA[8704];   // finL u32 | absb u16[32][136]
    __shared__ __align__(16) char regB[10320];  // acc int[20][128] | hls f32[20][129]
    __shared__ int st[24];
    __shared__ float bias_s[128], gamma_s[128], beta_s[128];

    unsigned* finL = (unsigned*)regA;
    unsigned short* absb = (unsigned short*)regA;
    int* acc = (int*)regB;
    float* hls = (float*)regB;

    int b = blockIdx.x, t = threadIdx.x;
    int start = bkt_start(b, N), end = bkt_start(b + 1, N);
    int nn = end - start;
    int wv = t >> 6, l = t & 63;

    // P0: coalesced copy of pre-swizzled W; bias/gamma/beta; st; zero acc
    for (int i = t; i < 2048; i += 512)
        ((uint4*)wb)[i] = ((const uint4*)wb_g)[i];
    if (t < 128) { bias_s[t] = bias[t]; gamma_s[t] = gamma[t]; beta_s[t] = beta[t]; }
    if (t <= nn) st[t] = stg[b * 32 + t];
    for (int i = t; i < 20 * 128; i += 512) acc[i] = 0;
    __syncthreads();
    int cntc = st[nn];
    // P1: coalesced fin load
    for (int i = t; i < cntc; i += 512) finL[i] = fin_g[b * MAXB + i];
    __syncthreads();

    // P2: balanced edge loop over sorted stream; register runs, flush at
    // dst boundaries with fixed-point ds_add.
    {
        int lo = (int)(((long long)cntc * wv) >> 3);
        int hi = (int)(((long long)cntc * (wv + 1)) >> 3);
        if (lo < hi) {
            int dl = 0;
            while (st[dl + 1] <= lo) ++dl;
            float a0 = 0.0f, a1 = 0.0f;
            int i = lo;
            while (i < hi) {
                if (i >= st[dl + 1]) {
                    atomicAdd(&acc[dl * 128 + l], (int)(a0 * FPSCALE));
                    atomicAdd(&acc[dl * 128 + 64 + l], (int)(a1 * FPSCALE));
                    a0 = 0.0f; a1 = 0.0f;
                    do { ++dl; } while (i >= st[dl + 1]);
                }
                int stop = st[dl + 1] < hi ? st[dl + 1] : hi;
                for (; i + 8 <= stop; i += 8) {
                    unsigned p[8], q[8];
#pragma unroll
                    for (int j = 0; j < 8; ++j) p[j] = finL[i + j];
#pragma unroll
                    for (int j = 0; j < 8; ++j) q[j] = xs[(p[j] & 0xffffu) * 64u + (unsigned)l];
#pragma unroll
                    for (int j = 0; j < 8; ++j) {
                        float wt = __uint_as_float(p[j] & 0xffff0000u);
                        a0 = fmaf(__uint_as_float(q[j] << 16), wt, a0);
                        a1 = fmaf(__uint_as_float(q[j] & 0xffff0000u), wt, a1);
                    }
                }
                for (; i < stop; ++i) {
                    unsigned p = finL[i];
                    float wt = __uint_as_float(p & 0xffff0000u);
                    unsigned q = xs[(p & 0xffffu) * 64u + (unsigned)l];
                    a0 = fmaf(__uint_as_float(q << 16), wt, a0);
                    a1 = fmaf(__uint_as_float(q & 0xffff0000u), wt, a1);
                }
            }
            atomicAdd(&acc[dl * 128 + l], (int)(a0 * FPSCALE));
            atomicAdd(&acc[dl * 128 + 64 + l], (int)(a1 * FPSCALE));
        }
    }
    __syncthreads();

    // P3: agg = acc*FPINV*dinv + x -> absb bf16 [32][136] (pad rows zero)
    for (int i = t; i < 32 * 128; i += 512) {
        int row = i >> 7, col = i & 127;
        unsigned short v = 0;
        if (row < nn) {
            float dv = rsqrtf((float)(st[row + 1] - st[row]) + 1.0f);
            float aggv = (float)acc[row * 128 + col] * FPINV * dv
                         + x[(start + row) * D + col];
            v = (unsigned short)bf16bits(aggv);
        }
        absb[row * 136 + col] = v;
    }
    __syncthreads();

    // P4: h = agg @ W via MFMA 16x16x32 bf16; + bias, exact GELU -> hls
    {
        int col = l & 15, quad = l >> 4;
#pragma unroll
        for (int ti = 0; ti < 2; ++ti) {
            int tid = wv * 2 + ti;          // 0..15
            int mt = tid >> 3, nt = tid & 7;
            f32x4 dacc = {0.0f, 0.0f, 0.0f, 0.0f};
#pragma unroll
            for (int kk = 0; kk < 4; ++kk) {
                bf16x8 av = *(const bf16x8*)&absb[(mt * 16 + col) * 136 + kk * 32 + quad * 8];
                bf16x8 bv = *(const bf16x8*)&wb[((kk * 4 + quad) * 128 + nt * 16 + col) * 8];
                dacc = __builtin_amdgcn_mfma_f32_16x16x32_bf16(av, bv, dacc, 0, 0, 0);
            }
#pragma unroll
            for (int r = 0; r < 4; ++r) {
                int m = mt * 16 + quad * 4 + r;
                int n = nt * 16 + col;
                if (m < 20) {
                    float hh = dacc[r] + bias_s[n];
                    hh = 0.5f * hh * (1.0f + erff(hh * 0.70710678f));
                    hls[m * 129 + n] = hh;
                }
            }
        }
    }
    __syncthreads();

    // P5: LayerNorm, one wave per row (lane l owns feats l, l+64) — no barriers
    for (int r = wv; r < nn; r += 8) {
        float h0 = hls[r * 129 + l];
        float h1 = hls[r * 129 + 64 + l];
        float v1 = h0 + h1;
        float v2 = h0 * h0 + h1 * h1;
#pragma unroll
        for (int o = 32; o > 0; o >>= 1) {
            v1 += __shfl_xor(v1, o, 64);
            v2 += __shfl_xor(v2, o, 64);
        }
        float mu = v1 * (1.0f / D);
        float var = v2 * (1.0f / D) - mu * mu;
        float rinv = rsqrtf(var + 1e-5f);
        int node = start + r;
        out[node * D + l] = (h0 - mu) * rinv * gamma_s[l] + beta_s[l];
        out[node * D + 64 + l] = (h1 - mu) * rinv * gamma_s[64 + l] + beta_s[64 + l];
    }
}

static inline size_t align256(size_t v) { return (v + 255) & ~(size_t)255; }

extern "C" void kernel_launch(void* const* d_in, const int* in_sizes, int n_in,
                              void* d_out, int out_size, void* d_ws, size_t ws_size,
                              hipStream_t stream) {
    const float* x     = (const float*)d_in[0];
    const int*   ei    = (const int*)d_in[1];
    const float* ew    = (const float*)d_in[2];
    const float* W     = (const float*)d_in[3];
    const float* b     = (const float*)d_in[4];
    const float* gamma = (const float*)d_in[5];
    const float* beta  = (const float*)d_in[6];
    float* out = (float*)d_out;

    const int E = in_sizes[2];                        // 640000
    const unsigned N = (unsigned)(in_sizes[0] / D);   // 10000
    const int chunk = (E + NBK - 1) / NBK;            // 2500
    const int* srcIdx = ei;
    const int* dstIdx = ei + E;

    char* ws = (char*)d_ws;
    size_t off = 0;
    uint2* tmp = (uint2*)(ws + off);         off += align256((size_t)E * 8);
    int* rp = (int*)(ws + off);              off += align256((size_t)NBK * (NB + 1) * 4);
    unsigned* xs = (unsigned*)(ws + off);    off += align256((size_t)N * 64 * 4);
    unsigned* fin_g = (unsigned*)(ws + off); off += align256((size_t)NB * MAXB * 4);
    int* stg = (int*)(ws + off);             off += align256((size_t)NB * 32 * 4);
    unsigned short* wb_g = (unsigned short*)(ws + off); off += align256((size_t)16384 * 2);
    (void)ws_size; (void)n_in; (void)out_size;

    k_scatter<<<NBK + 8, 1024, 0, stream>>>(srcIdx, dstIdx, ew, W, tmp, rp, wb_g, E, chunk, N);
    k_build<<<NB, 512, 0, stream>>>(x, tmp, rp, fin_g, stg, xs, chunk, N);
    k_mega<<<NB, 512, 0, stream>>>(x, xs, fin_g, stg, wb_g, b, gamma, beta, out, N);
}